// Round 2
// baseline (140.549 us; speedup 1.0000x reference)
//
#include <hip/hip_runtime.h>

// AbsolutePositionEncoding: out[b][s][e] = E[s>>3][e]
//   b in [0,64), s in [0,2048), e in [0,256), ALL FP32 (dtype forensics from
//   round-2 of the previous session: storage is fp32; d_in[0]=x unused,
//   d_in[1]=E 512x256 fp32).
//
// ROUND-0 THEORY (unchanged): bench dur_us (132.8) = harness poison-fill
// (~83 us, fillBufferAligned in rocprof top-5) + our kernel (~49 us). The old
// kernel was latency/wave-launch-bound: 131072 waves x 1 dependent load->store
// each (~920 cy/wave effective), reaching only ~2.7 TB/s vs the 6.4 TB/s the
// fill demonstrates. Fix: output = one 2 MiB [S,E] plane broadcast 64x over
// batch. Each thread owns one (s,e4), loads its E float4 ONCE, stores it to
// BATCH_PER_BLOCK=16 batch planes (2 MiB stride, 1 KiB/wave coalesced stores).
// Waves drop 16x (131072 -> 8192); 2048 blocks = 8 blocks/CU = full occupancy.
// Nontemporal stores: 134 MB output can't be L2-resident (32 MiB aggregate).
//
// ROUND-1 FIX: __builtin_nontemporal_store rejects HIP_vector_type<float,4>;
// needs a native clang vector. Use ext_vector_type(4) float for the store.

typedef float floatx4 __attribute__((ext_vector_type(4)));

constexpr unsigned BATCH           = 64;
constexpr unsigned SEQ             = 2048;
constexpr unsigned EDIM            = 256;
constexpr unsigned VEC_PER_ROW     = EDIM / 4;           // 64 float4 per (b,s) row
constexpr unsigned PLANE_VEC       = SEQ * VEC_PER_ROW;  // 131072 float4 per batch plane (2 MiB)
constexpr unsigned BLOCK           = 256;
constexpr unsigned BATCH_PER_BLOCK = 16;                 // stores per thread

__global__ __launch_bounds__(BLOCK)
void ape_broadcast_kernel(const floatx4* __restrict__ E, floatx4* __restrict__ out) {
    // v indexes the [S, E/4] plane; consecutive lanes -> consecutive 16 B chunks.
    unsigned v   = blockIdx.x * BLOCK + threadIdx.x;  // < 131072
    unsigned e4  = v & (VEC_PER_ROW - 1);             // float4 index within row
    unsigned s   = v >> 6;                            // v < PLANE_VEC so s < 2048
    unsigned obj = s >> 3;                            // token -> object (s / 8)

    // One read per thread, reused for 16 stores. A wave reads one full E row
    // (1 KiB, L2-hot: E is 512 KiB total).
    floatx4 val = E[obj * VEC_PER_ROW + e4];

    unsigned b0 = blockIdx.y * BATCH_PER_BLOCK;
    floatx4* p  = out + (size_t)b0 * PLANE_VEC + v;
#pragma unroll
    for (unsigned i = 0; i < BATCH_PER_BLOCK; ++i) {
        __builtin_nontemporal_store(val, p);          // 2 MiB stride per step,
        p += PLANE_VEC;                               // still coalesced per wave
    }
}

extern "C" void kernel_launch(void* const* d_in, const int* in_sizes, int n_in,
                              void* d_out, int out_size, void* d_ws, size_t ws_size,
                              hipStream_t stream) {
    const floatx4* E = (const floatx4*)d_in[1];  // documented dict order
    floatx4* out     = (floatx4*)d_out;

    dim3 grid(PLANE_VEC / BLOCK,               // 512 plane blocks
              BATCH / BATCH_PER_BLOCK);        // 4 batch groups -> 2048 blocks
    ape_broadcast_kernel<<<grid, dim3(BLOCK), 0, stream>>>(E, out);
}

// Round 3
// 133.462 us; speedup vs baseline: 1.0531x; 1.0531x over previous
//
#include <hip/hip_runtime.h>

// AbsolutePositionEncoding: out[b][s][e] = E[s>>3][e]
//   b in [0,64), s in [0,2048), e in [0,256), ALL FP32.
//   d_in[0] = x (unused), d_in[1] = E (512x256 fp32).
//
// ROUND-3 THEORY (rounds 0-2 post-mortem): dur_us = harness poison-fill
// (~85 us fixed) + our kernel (~50 us @ 2.6 TB/s stores). Wave-launch-latency
// theory falsified in round 2 (16x wave cut + load amortization = no change).
// The rocclr fill sustains 6.3 TB/s at ~10% occupancy: ~800 waves with LONG
// sequential per-wave runs. Our variants used 8192+ resident waves whose
// streams are 1 KiB bursts that then jump (die / hop 2 MiB) -> more
// concurrent write streams than HBM row buffers -> row thrash -> 2.6 TB/s.
// FIX: fill-identical structure. Each WAVE owns a contiguous 64 KiB run
// (4096 float4 = 64 seq-rows; 32 waves per 2 MiB batch plane, exact, no
// crossing). 8 wave-uniform E-row loads (L1/L2-hot), each reused for 8
// sequential 1 KiB stores. 512 blocks = 2048 long sequential streams.
// Plain stores (nt was neutral in round 2; fill uses plain).
//
// PREDICTION: kernel 50 -> ~25 us (2.6 -> ~5.5 TB/s), dur_us -> ~108-116.

typedef float floatx4 __attribute__((ext_vector_type(4)));

constexpr unsigned BATCH        = 64;
constexpr unsigned SEQ          = 2048;
constexpr unsigned EDIM         = 256;
constexpr unsigned VEC_PER_ROW  = EDIM / 4;              // 64 float4 per row
constexpr unsigned TOTAL_VEC    = BATCH * SEQ * VEC_PER_ROW;  // 8,388,608
constexpr unsigned BLOCK        = 256;                   // 4 waves
constexpr unsigned GRID         = 512;                   // 2048 waves total
constexpr unsigned WAVE_VEC     = TOTAL_VEC / (GRID * 4);     // 4096 float4 = 64 KiB run
constexpr unsigned ROWS_PER_WAVE = WAVE_VEC / VEC_PER_ROW;    // 64 seq-rows
constexpr unsigned OBJS_PER_WAVE = ROWS_PER_WAVE / 8;         // 8 objects

static_assert(WAVE_VEC * GRID * 4 == TOTAL_VEC, "exact cover");
static_assert((SEQ * VEC_PER_ROW) % WAVE_VEC == 0, "no plane crossing");

__global__ __launch_bounds__(BLOCK)
void ape_broadcast_kernel(const floatx4* __restrict__ E, floatx4* __restrict__ out) {
    unsigned lane = threadIdx.x & 63;
    unsigned wave = blockIdx.x * (BLOCK / 64) + (threadIdx.x >> 6);  // < 2048
    unsigned base = wave * WAVE_VEC;              // float4 index of run start
    unsigned s0   = (base >> 6) & (SEQ - 1);      // multiple of 64
    unsigned obj0 = s0 >> 3;                      // 8-aligned

    floatx4* p = out + base + lane;               // lane-interleaved, 1 KiB/wave/step
#pragma unroll
    for (unsigned oj = 0; oj < OBJS_PER_WAVE; ++oj) {
        // Wave-uniform row: 64 lanes read one 1 KiB E row, L1/L2-hot.
        floatx4 val = E[(obj0 + oj) * VEC_PER_ROW + lane];
#pragma unroll
        for (unsigned r = 0; r < 8; ++r) {        // 8 seq-rows share this object
            *p = val;                             // sequential 1 KiB steps
            p += VEC_PER_ROW;
        }
    }
}

extern "C" void kernel_launch(void* const* d_in, const int* in_sizes, int n_in,
                              void* d_out, int out_size, void* d_ws, size_t ws_size,
                              hipStream_t stream) {
    const floatx4* E = (const floatx4*)d_in[1];   // documented dict order
    floatx4* out     = (floatx4*)d_out;
    ape_broadcast_kernel<<<GRID, BLOCK, 0, stream>>>(E, out);
}